// Round 2
// baseline (145.124 us; speedup 1.0000x reference)
//
#include <hip/hip_runtime.h>
#include <hip/hip_bf16.h>

using shortx4 = __attribute__((ext_vector_type(4))) short;
using short8  = __attribute__((ext_vector_type(8))) short;
using floatx4 = __attribute__((ext_vector_type(4))) float;

// ---------------------------------------------------------------------------
// prepack: weights fp32 -> bf16 in MFMA-B-fragment-tiled layout.
// Fragment (nblk, kstep) occupies 64 lanes x 8 elems contiguous; lane l holds
// B[n = nblk*16 + (l&15)][k = kstep*32 + (l>>4)*8 .. +7]  (verified B-frag
// mapping: row=lane&15, k=quad*8+j). Loading a frag = one coalesced 1-KiB
// global_load_dwordx4 per wave.
//  wsb_t: from w_sample [256 s][1024 k]  -> 16 nblk x 32 kstep   (262144 elems)
//  wib_t: from w_init  [1024 k'][256 s]  -> 64 nblk x  8 kstep   (262144 elems)
// ---------------------------------------------------------------------------
__global__ __launch_bounds__(256) void prepack_kernel(const float* __restrict__ w_sample,
                                                      const float* __restrict__ w_init,
                                                      __hip_bfloat16* __restrict__ wsb_t,
                                                      __hip_bfloat16* __restrict__ wib_t) {
    const int tg   = blockIdx.x * 256 + threadIdx.x;   // 0..65535
    const int lane = tg & 63;
    const int l16  = lane & 15, quad = lane >> 4;
    const float* src;
    __hip_bfloat16* dst;
    if (tg < 32768) {
        const int chunk = tg >> 6;                     // 0..511: nblk=chunk>>5, kstep=chunk&31
        const int n = (chunk >> 5) * 16 + l16;
        const int k = (chunk & 31) * 32 + quad * 8;
        src = w_sample + (size_t)n * 1024 + k;
        dst = wsb_t + (size_t)tg * 8;
    } else {
        const int t2 = tg - 32768;
        const int chunk = t2 >> 6;                     // 0..511: nblk=chunk>>3, kstep=chunk&7
        const int n = (chunk >> 3) * 16 + l16;
        const int k = (chunk & 7) * 32 + quad * 8;
        src = w_init + (size_t)n * 256 + k;
        dst = wib_t + (size_t)t2 * 8;
    }
    floatx4 v0 = *(const floatx4*)(src);
    floatx4 v1 = *(const floatx4*)(src + 4);
    union { short8 s; __hip_bfloat16 h[8]; } u;
#pragma unroll
    for (int i = 0; i < 4; ++i) {
        u.h[i]     = __float2bfloat16(v0[i]);
        u.h[4 + i] = __float2bfloat16(v1[i]);
    }
    *(short8*)dst = u.s;
}

// ---------------------------------------------------------------------------
// fused (v2: 512 threads / 8 waves per block, grid 512 = 2 blocks/CU,
//        16 waves/CU = 4 waves/SIMD -- was 2; attacks L2-latency bound).
// Per block = 32 patches sharing (b, nh) => one contiguous 32-row image slab.
//  Phase 1: meas[32x256] = patch[32x1024] @ Ws^T  (K=1024, 16 iters BK=64)
//    - As [32][72] bf16 ping-pong in LDS (pad +8: 144B row stride makes the
//      A-frag ds_read_b128 2-way = free; old 128B stride was 16-way conflict),
//      cvt from fp32 inline, ONE barrier per iter; staging = 1 float4/thread,
//      fully contiguous 8KB slab. B-frags register-direct from wsb_t (L2).
//    - 8 waves split N=256 into 32-col ranges; wave tile 32x32 (MI=2,NI=2).
//  meas -> LDS [32][264] (pad 8: 2-way = free).
//  Phase 2 (barrier-free): rec[32x1024] = meas @ Wi^T (K=256); each wave owns
//    128 cols as 2 chunks of 64 (MI=2,NI=4); B-frags register-direct from
//    wib_t (L2); fold-epilogue per chunk straight to y fp32.
// Verified layouts used throughout: A/B frag row=lane&15, k=quad*8+j;
// C/D col=lane&15, row=quad*4+reg.
// ---------------------------------------------------------------------------
__global__ __launch_bounds__(512, 4) void fused_kernel(const float* __restrict__ x,
                                                       const __hip_bfloat16* __restrict__ wsb_t,
                                                       const __hip_bfloat16* __restrict__ wib_t,
                                                       float* __restrict__ Y) {
    __shared__ __hip_bfloat16 As[2][32 * 72];  // ping-pong A tile, padded rows
    __shared__ __hip_bfloat16 Ms[32 * 264];    // meas tile, row stride 264

    const int tid  = threadIdx.x;
    const int wave = tid >> 6, lane = tid & 63;
    const int quad = lane >> 4, l16 = lane & 15;
    const int blk  = blockIdx.x;               // blk = b*32 + nh

    // A staging: thread t loads float4 at slab offset t*4 (contiguous);
    // maps to patch m=(t&255)>>3, in-patch row srow=t>>8, kw=(t&7)*4.
    const float* srcX = x + (size_t)blk * 32768 + tid * 4;
    const int sidx = (((tid & 255) >> 3) * 72) + ((tid >> 8) * 32) + ((tid & 7) * 4);

    // register-direct B-frag bases (each wave reads its private strip)
    const __hip_bfloat16* baseW1 = wsb_t + (size_t)wave * 32768 + lane * 8;  // nblk {2w,2w+1}
    const __hip_bfloat16* baseW2 = wib_t + (size_t)wave * 32768 + lane * 8;  // nblk [8w,8w+8)

    floatx4 acc[2][2];
#pragma unroll
    for (int i = 0; i < 2; ++i)
#pragma unroll
        for (int j = 0; j < 2; ++j) acc[i][j] = {0.f, 0.f, 0.f, 0.f};

    // ---------------- phase 1 ----------------
    floatx4 v = *(const floatx4*)(srcX);
    srcX += 2048;

    for (int it = 0; it < 16; ++it) {
        union { shortx4 s; __hip_bfloat16 h[4]; } u;
#pragma unroll
        for (int q = 0; q < 4; ++q) u.h[q] = __float2bfloat16(v[q]);
        *(shortx4*)&As[it & 1][sidx] = u.s;
        __syncthreads();                        // write(it) visible; prev reads done
        if (it < 15) {                          // prefetch next slab (latency hides
            v = *(const floatx4*)(srcX);        //  under the MFMA below)
            srcX += 2048;
        }
        const __hip_bfloat16* Ap = As[it & 1];
#pragma unroll
        for (int kk = 0; kk < 2; ++kk) {
            short8 af[2], bfr[2];
#pragma unroll
            for (int i = 0; i < 2; ++i)
                af[i] = *(const short8*)&Ap[(i * 16 + l16) * 72 + kk * 32 + quad * 8];
#pragma unroll
            for (int j = 0; j < 2; ++j)
                bfr[j] = *(const short8*)(baseW1 + (size_t)(j * 32 + it * 2 + kk) * 512);
#pragma unroll
            for (int i = 0; i < 2; ++i)
#pragma unroll
                for (int j = 0; j < 2; ++j)
                    acc[i][j] = __builtin_amdgcn_mfma_f32_16x16x32_bf16(af[i], bfr[j], acc[i][j], 0, 0, 0);
        }
    }

    // meas (C-layout) -> Ms row-major [m][s]; wave strip = cols [32w, 32w+32)
#pragma unroll
    for (int i = 0; i < 2; ++i)
#pragma unroll
        for (int r = 0; r < 4; ++r) {
            const int row = i * 16 + quad * 4 + r;
#pragma unroll
            for (int j = 0; j < 2; ++j)
                Ms[row * 264 + wave * 32 + j * 16 + l16] = __float2bfloat16(acc[i][j][r]);
        }
    __syncthreads();

    // ---------------- phase 2 (barrier-free) ----------------
    // wave owns rec cols [wave*128, wave*128+128) as 2 chunks of 64
    float* ybase = Y + (size_t)blk * 32768;
#pragma unroll 1
    for (int c = 0; c < 2; ++c) {
        floatx4 a2[2][4];
#pragma unroll
        for (int i = 0; i < 2; ++i)
#pragma unroll
            for (int j = 0; j < 4; ++j) a2[i][j] = {0.f, 0.f, 0.f, 0.f};
        const __hip_bfloat16* w2 = baseW2 + (size_t)c * 16384;   // (c*4)*4096
#pragma unroll
        for (int ks = 0; ks < 8; ++ks) {
            short8 af[2], bfr[4];
#pragma unroll
            for (int i = 0; i < 2; ++i)
                af[i] = *(const short8*)&Ms[(i * 16 + l16) * 264 + ks * 32 + quad * 8];
#pragma unroll
            for (int j = 0; j < 4; ++j)
                bfr[j] = *(const short8*)(w2 + (size_t)j * 4096 + ks * 512);
#pragma unroll
            for (int i = 0; i < 2; ++i)
#pragma unroll
                for (int j = 0; j < 4; ++j)
                    a2[i][j] = __builtin_amdgcn_mfma_f32_16x16x32_bf16(af[i], bfr[j], a2[i][j], 0, 0, 0);
        }
        // fold epilogue: col = wave*128 + c*64 + j*16 + l16 -> (kh,kw)
#pragma unroll
        for (int i = 0; i < 2; ++i)
#pragma unroll
            for (int r = 0; r < 4; ++r) {
                const int m = i * 16 + quad * 4 + r;
#pragma unroll
                for (int j = 0; j < 4; ++j) {
                    const int col = wave * 128 + c * 64 + j * 16 + l16;
                    const int kh = col >> 5, kw = col & 31;
                    ybase[kh * 1024 + m * 32 + kw] = a2[i][j][r];
                }
            }
    }
}

// ---------------------------------------------------------------------------
// Workspace: wsb_t bf16 [262144] @ 0 (524288 B); wib_t bf16 [262144]
// @ 524288 (524288 B). Total 1 MB.
// ---------------------------------------------------------------------------
extern "C" void kernel_launch(void* const* d_in, const int* in_sizes, int n_in,
                              void* d_out, int out_size, void* d_ws, size_t ws_size,
                              hipStream_t stream) {
    const float* x        = (const float*)d_in[0];
    const float* w_sample = (const float*)d_in[1];
    const float* w_init   = (const float*)d_in[2];
    float* y = (float*)d_out;
    char* ws = (char*)d_ws;

    __hip_bfloat16* wsb_t = (__hip_bfloat16*)(ws);
    __hip_bfloat16* wib_t = (__hip_bfloat16*)(ws + (size_t)524288);

    prepack_kernel<<<256, 256, 0, stream>>>(w_sample, w_init, wsb_t, wib_t);
    fused_kernel<<<512, 512, 0, stream>>>(x, wsb_t, wib_t, y);
}

// Round 3
// 144.967 us; speedup vs baseline: 1.0011x; 1.0011x over previous
//
#include <hip/hip_runtime.h>
#include <hip/hip_bf16.h>

using short8  = __attribute__((ext_vector_type(8))) short;
using floatx4 = __attribute__((ext_vector_type(4))) float;

// ---------------------------------------------------------------------------
// prepack: weights fp32 -> bf16 in MFMA-B-fragment-tiled layout.
// Fragment (nblk, kstep) occupies 64 lanes x 8 elems contiguous; lane l holds
// B[n = nblk*16 + (l&15)][k = kstep*32 + (l>>4)*8 .. +7]  (verified B-frag
// mapping: row=lane&15, k=quad*8+j). Loading a frag = one coalesced 1-KiB
// global_load_dwordx4 per wave.
//  wsb_t: from w_sample [256 s][1024 k]  -> 16 nblk x 32 kstep   (262144 elems)
//  wib_t: from w_init  [1024 k'][256 s]  -> 64 nblk x  8 kstep   (262144 elems)
// ---------------------------------------------------------------------------
__global__ __launch_bounds__(256) void prepack_kernel(const float* __restrict__ w_sample,
                                                      const float* __restrict__ w_init,
                                                      __hip_bfloat16* __restrict__ wsb_t,
                                                      __hip_bfloat16* __restrict__ wib_t) {
    const int tg   = blockIdx.x * 256 + threadIdx.x;   // 0..65535
    const int lane = tg & 63;
    const int l16  = lane & 15, quad = lane >> 4;
    const float* src;
    __hip_bfloat16* dst;
    if (tg < 32768) {
        const int chunk = tg >> 6;                     // 0..511: nblk=chunk>>5, kstep=chunk&31
        const int n = (chunk >> 5) * 16 + l16;
        const int k = (chunk & 31) * 32 + quad * 8;
        src = w_sample + (size_t)n * 1024 + k;
        dst = wsb_t + (size_t)tg * 8;
    } else {
        const int t2 = tg - 32768;
        const int chunk = t2 >> 6;                     // 0..511: nblk=chunk>>3, kstep=chunk&7
        const int n = (chunk >> 3) * 16 + l16;
        const int k = (chunk & 7) * 32 + quad * 8;
        src = w_init + (size_t)n * 256 + k;
        dst = wib_t + (size_t)t2 * 8;
    }
    floatx4 v0 = *(const floatx4*)(src);
    floatx4 v1 = *(const floatx4*)(src + 4);
    union { short8 s; __hip_bfloat16 h[8]; } u;
#pragma unroll
    for (int i = 0; i < 4; ++i) {
        u.h[i]     = __float2bfloat16(v0[i]);
        u.h[4 + i] = __float2bfloat16(v1[i]);
    }
    *(short8*)dst = u.s;
}

// ---------------------------------------------------------------------------
// fused v3: round-0 structure (256 thr / 4 waves, grid 512 = 2 blocks/CU,
// wave tile 32x64) + two changes:
//  (a) phase-1 B-fragment REGISTER double-buffer: iteration it+1's 8 B-frags
//      are issued right after it's barrier and consumed next iteration, so
//      the per-barrier vmcnt(0) drain completes prefetches instead of
//      preceding cold L2 loads (was: ~250cy exposed latency x16 iters).
//      Manual unroll-by-2 with named bA/bB (no runtime-indexed arrays).
//  (b) phase-2 swapped-operand MFMA: a2 = mfma(bfr, af) -> D[row]=n, D[col]=m.
//      Lane then holds 4 CONSECUTIVE rec-cols (r=0..3) for one patch m ->
//      epilogue is one global_store_dwordx4 per (i,j) (32 stores/wave, was
//      128 scattered dwords + per-element addr math).
// As padded [32][72] (144B row stride; b128 reads at 2-lanes/bank-group min).
// Verified layouts: A/B frag row=lane&15, k=quad*8+j; C/D col=lane&15,
// row=quad*4+reg (operand-swap transposes roles, not the mapping).
// ---------------------------------------------------------------------------
#define PH1_BODY(IT, BCUR, BNEXT, PREFETCH)                                        \
  {                                                                                \
    union { short8 s; __hip_bfloat16 h[8]; } u;                                    \
    _Pragma("unroll") for (int q = 0; q < 4; ++q) {                                \
      u.h[q]     = __float2bfloat16(v0[q]);                                        \
      u.h[4 + q] = __float2bfloat16(v1[q]);                                        \
    }                                                                              \
    *(short8*)&As[(IT) & 1][sidx] = u.s;                                           \
    __syncthreads();                                                               \
    if (PREFETCH) {                                                                \
      v0 = *(const floatx4*)(srcX);                                                \
      v1 = *(const floatx4*)(srcX + 4);                                            \
      srcX += 2048;                                                                \
      _Pragma("unroll") for (int kk = 0; kk < 2; ++kk)                             \
        _Pragma("unroll") for (int j = 0; j < 4; ++j)                              \
          BNEXT[kk * 4 + j] =                                                      \
              *(const short8*)(baseW1 + (size_t)(j * 32 + ((IT) + 1) * 2 + kk) * 512); \
    }                                                                              \
    const __hip_bfloat16* Ap = As[(IT) & 1];                                       \
    _Pragma("unroll") for (int kk = 0; kk < 2; ++kk) {                             \
      short8 af[2];                                                                \
      _Pragma("unroll") for (int i = 0; i < 2; ++i)                                \
        af[i] = *(const short8*)&Ap[(i * 16 + l16) * 72 + kk * 32 + quad * 8];     \
      _Pragma("unroll") for (int i = 0; i < 2; ++i)                                \
        _Pragma("unroll") for (int j = 0; j < 4; ++j)                              \
          acc[i][j] = __builtin_amdgcn_mfma_f32_16x16x32_bf16(af[i], BCUR[kk * 4 + j], \
                                                              acc[i][j], 0, 0, 0);  \
    }                                                                              \
  }

__global__ __launch_bounds__(256, 2) void fused_kernel(const float* __restrict__ x,
                                                       const __hip_bfloat16* __restrict__ wsb_t,
                                                       const __hip_bfloat16* __restrict__ wib_t,
                                                       float* __restrict__ Y) {
    __shared__ __hip_bfloat16 As[2][32 * 72];  // ping-pong A tile [32][72]
    __shared__ __hip_bfloat16 Ms[32 * 264];    // meas tile, row stride 264

    const int tid  = threadIdx.x;
    const int wave = tid >> 6, lane = tid & 63;
    const int quad = lane >> 4, l16 = lane & 15;
    const int blk  = blockIdx.x;               // blk = b*32 + nh

    // A staging: thread -> (row = tid>>3, 8 consecutive k at k8=(tid&7)*8)
    const float* srcX = x + (size_t)blk * 32768
                        + ((tid & 7) >> 2) * 1024 + (tid >> 3) * 32 + (tid & 3) * 8;
    const int sidx = (tid >> 3) * 72 + (tid & 7) * 8;

    // register-direct B-frag bases (each wave reads its private quarter)
    const __hip_bfloat16* baseW1 = wsb_t + (size_t)wave * 65536 + lane * 8;
    const __hip_bfloat16* baseW2 = wib_t + (size_t)wave * 16384 + lane * 8;

    floatx4 acc[2][4];
#pragma unroll
    for (int i = 0; i < 2; ++i)
#pragma unroll
        for (int j = 0; j < 4; ++j) acc[i][j] = {0.f, 0.f, 0.f, 0.f};

    // ---------------- phase 1 ----------------
    floatx4 v0 = *(const floatx4*)(srcX);
    floatx4 v1 = *(const floatx4*)(srcX + 4);
    srcX += 2048;

    short8 bA[8], bB[8];                       // B-frag double buffer (it / it+1)
#pragma unroll
    for (int kk = 0; kk < 2; ++kk)
#pragma unroll
        for (int j = 0; j < 4; ++j)
            bA[kk * 4 + j] = *(const short8*)(baseW1 + (size_t)(j * 32 + kk) * 512);

    for (int it2 = 0; it2 < 8; ++it2) {
        const int it = it2 * 2;
        PH1_BODY(it,     bA, bB, 1);
        PH1_BODY(it + 1, bB, bA, (it2 < 7));
    }

    // meas (C-layout) -> Ms row-major [m][s]; wave strip = cols [64w, 64w+64)
#pragma unroll
    for (int i = 0; i < 2; ++i)
#pragma unroll
        for (int r = 0; r < 4; ++r) {
            const int row = i * 16 + quad * 4 + r;
#pragma unroll
            for (int j = 0; j < 4; ++j)
                Ms[row * 264 + wave * 64 + j * 16 + l16] = __float2bfloat16(acc[i][j][r]);
        }
    __syncthreads();

    // ---------------- phase 2 (barrier-free, swapped operands) ----------------
    float* ybase = Y + (size_t)blk * 32768;
#pragma unroll 1
    for (int c = 0; c < 4; ++c) {
        floatx4 a2[2][4];
#pragma unroll
        for (int i = 0; i < 2; ++i)
#pragma unroll
            for (int j = 0; j < 4; ++j) a2[i][j] = {0.f, 0.f, 0.f, 0.f};
        const __hip_bfloat16* w2 = baseW2 + (size_t)c * 65536;
#pragma unroll
        for (int ks = 0; ks < 8; ++ks) {
            short8 af[2], bfr[4];
#pragma unroll
            for (int i = 0; i < 2; ++i)
                af[i] = *(const short8*)&Ms[(i * 16 + l16) * 264 + ks * 32 + quad * 8];
#pragma unroll
            for (int j = 0; j < 4; ++j)
                bfr[j] = *(const short8*)(w2 + (size_t)j * 4096 + ks * 512);
            // SWAPPED: D[row = n-local = quad*4+r][col = m-local = l16]
#pragma unroll
            for (int i = 0; i < 2; ++i)
#pragma unroll
                for (int j = 0; j < 4; ++j)
                    a2[i][j] = __builtin_amdgcn_mfma_f32_16x16x32_bf16(bfr[j], af[i], a2[i][j], 0, 0, 0);
        }
        // epilogue: n = c*256 + wave*64 + j*16 + quad*4 + r (r = vector lane of a2),
        //           m = i*16 + l16.  4 consecutive n => one dwordx4 store.
#pragma unroll
        for (int i = 0; i < 2; ++i)
#pragma unroll
            for (int j = 0; j < 4; ++j) {
                const int nb = c * 256 + wave * 64 + j * 16 + quad * 4;
                float* p = ybase + (nb >> 5) * 1024 + (i * 16 + l16) * 32 + (nb & 31);
                *(floatx4*)p = a2[i][j];
            }
    }
}

// ---------------------------------------------------------------------------
// Workspace: wsb_t bf16 [262144] @ 0 (524288 B); wib_t bf16 [262144]
// @ 524288 (524288 B). Total 1 MB.
// ---------------------------------------------------------------------------
extern "C" void kernel_launch(void* const* d_in, const int* in_sizes, int n_in,
                              void* d_out, int out_size, void* d_ws, size_t ws_size,
                              hipStream_t stream) {
    const float* x        = (const float*)d_in[0];
    const float* w_sample = (const float*)d_in[1];
    const float* w_init   = (const float*)d_in[2];
    float* y = (float*)d_out;
    char* ws = (char*)d_ws;

    __hip_bfloat16* wsb_t = (__hip_bfloat16*)(ws);
    __hip_bfloat16* wib_t = (__hip_bfloat16*)(ws + (size_t)524288);

    prepack_kernel<<<256, 256, 0, stream>>>(w_sample, w_init, wsb_t, wib_t);
    fused_kernel<<<512, 256, 0, stream>>>(x, wsb_t, wib_t, y);
}

// Round 4
// 135.208 us; speedup vs baseline: 1.0733x; 1.0722x over previous
//
#include <hip/hip_runtime.h>
#include <hip/hip_bf16.h>

using short8  = __attribute__((ext_vector_type(8))) short;
using floatx4 = __attribute__((ext_vector_type(4))) float;

// ---------------------------------------------------------------------------
// prepack: weights fp32 -> bf16 in MFMA-B-fragment-tiled layout.
// Fragment (nblk, kstep) occupies 64 lanes x 8 elems contiguous; lane l holds
// B[n = nblk*16 + (l&15)][k = kstep*32 + (l>>4)*8 .. +7]  (verified B-frag
// mapping: row=lane&15, k=quad*8+j). Loading a frag = one coalesced 1-KiB
// global_load_dwordx4 per wave.
//  wsb_t: from w_sample [256 s][1024 k]  -> 16 nblk x 32 kstep   (262144 elems)
//  wib_t: from w_init  [1024 k'][256 s]  -> 64 nblk x  8 kstep   (262144 elems)
// ---------------------------------------------------------------------------
__global__ __launch_bounds__(256) void prepack_kernel(const float* __restrict__ w_sample,
                                                      const float* __restrict__ w_init,
                                                      __hip_bfloat16* __restrict__ wsb_t,
                                                      __hip_bfloat16* __restrict__ wib_t) {
    const int tg   = blockIdx.x * 256 + threadIdx.x;   // 0..65535
    const int lane = tg & 63;
    const int l16  = lane & 15, quad = lane >> 4;
    const float* src;
    __hip_bfloat16* dst;
    if (tg < 32768) {
        const int chunk = tg >> 6;                     // 0..511: nblk=chunk>>5, kstep=chunk&31
        const int n = (chunk >> 5) * 16 + l16;
        const int k = (chunk & 31) * 32 + quad * 8;
        src = w_sample + (size_t)n * 1024 + k;
        dst = wsb_t + (size_t)tg * 8;
    } else {
        const int t2 = tg - 32768;
        const int chunk = t2 >> 6;                     // 0..511: nblk=chunk>>3, kstep=chunk&7
        const int n = (chunk >> 3) * 16 + l16;
        const int k = (chunk & 7) * 32 + quad * 8;
        src = w_init + (size_t)n * 256 + k;
        dst = wib_t + (size_t)t2 * 8;
    }
    floatx4 v0 = *(const floatx4*)(src);
    floatx4 v1 = *(const floatx4*)(src + 4);
    union { short8 s; __hip_bfloat16 h[8]; } u;
#pragma unroll
    for (int i = 0; i < 4; ++i) {
        u.h[i]     = __float2bfloat16(v0[i]);
        u.h[4 + i] = __float2bfloat16(v1[i]);
    }
    *(short8*)dst = u.s;
}

// ---------------------------------------------------------------------------
// fused v4 = round-0 structure (256 thr / 4 waves, grid 512 = 2 blocks/CU,
// wave tile 32x64, plain loops the compiler schedules itself) with ONE
// structural change: phase-1 BK = 128 (8 iterations instead of 16).
//  - halves the per-iteration fixed cost (barrier + vmcnt/lgkm drain)
//  - 16 B-frag loads + 32 MFMAs per interval: 2x load batch MLP, 2x compute
//    to hide the x prefetch (HBM first-touch ~900cy) under
//  - As [32][136] ping-pong (stride 272B: 16B-aligned b128 reads, pad keeps
//    read conflicts in the measured ~0.65M-cycle class = ~2.5%, not a limiter)
//  - staging: thread t loads 64B (16 consecutive floats = 4x floatx4) of the
//    16KB slab chunk [it*4096 + t*16 ...); maps to one contiguous 32B LDS
//    write at As[m][r*32+kw0], m=(t>>1)&31, r=t>>6, kw0=(t&1)*16.
// Phase 2 identical to the proven round-0 form.
// Verified layouts: A/B frag row=lane&15, k=quad*8+j; C/D col=lane&15,
// row=quad*4+reg.
// ---------------------------------------------------------------------------
__global__ __launch_bounds__(256, 2) void fused_kernel(const float* __restrict__ x,
                                                       const __hip_bfloat16* __restrict__ wsb_t,
                                                       const __hip_bfloat16* __restrict__ wib_t,
                                                       float* __restrict__ Y) {
    __shared__ __hip_bfloat16 As[2][32 * 136]; // ping-pong A tile [32][136], BK=128
    __shared__ __hip_bfloat16 Ms[32 * 264];    // meas tile, row stride 264

    const int tid  = threadIdx.x;
    const int wave = tid >> 6, lane = tid & 63;
    const int quad = lane >> 4, l16 = lane & 15;
    const int blk  = blockIdx.x;               // blk = b*32 + nh

    // A staging (see header): 16 consecutive floats per thread per iter
    const float* srcX = x + (size_t)blk * 32768 + tid * 16;
    const int sidx = ((tid >> 1) & 31) * 136 + (tid >> 6) * 32 + (tid & 1) * 16;

    // register-direct B-frag bases (each wave reads its private quarter)
    const __hip_bfloat16* baseW1 = wsb_t + (size_t)wave * 65536 + lane * 8;
    const __hip_bfloat16* baseW2 = wib_t + (size_t)wave * 16384 + lane * 8;

    floatx4 acc[2][4];
#pragma unroll
    for (int i = 0; i < 2; ++i)
#pragma unroll
        for (int j = 0; j < 4; ++j) acc[i][j] = {0.f, 0.f, 0.f, 0.f};

    // ---------------- phase 1 (8 iters, BK=128) ----------------
    floatx4 v0 = *(const floatx4*)(srcX);
    floatx4 v1 = *(const floatx4*)(srcX + 4);
    floatx4 v2 = *(const floatx4*)(srcX + 8);
    floatx4 v3 = *(const floatx4*)(srcX + 12);
    srcX += 4096;

    for (int it = 0; it < 8; ++it) {
        union { short8 s; __hip_bfloat16 h[8]; } ua, ub;
#pragma unroll
        for (int q = 0; q < 4; ++q) {
            ua.h[q]     = __float2bfloat16(v0[q]);
            ua.h[4 + q] = __float2bfloat16(v1[q]);
            ub.h[q]     = __float2bfloat16(v2[q]);
            ub.h[4 + q] = __float2bfloat16(v3[q]);
        }
        *(short8*)&As[it & 1][sidx]     = ua.s;
        *(short8*)&As[it & 1][sidx + 8] = ub.s;
        __syncthreads();                        // write(it) visible; prev reads done
        if (it < 7) {                           // prefetch next 16KB chunk (hides
            v0 = *(const floatx4*)(srcX);       //  under the 32 MFMAs below)
            v1 = *(const floatx4*)(srcX + 4);
            v2 = *(const floatx4*)(srcX + 8);
            v3 = *(const floatx4*)(srcX + 12);
            srcX += 4096;
        }
        const __hip_bfloat16* Ap = As[it & 1];
#pragma unroll
        for (int kk = 0; kk < 4; ++kk) {
            short8 af[2], bfr[4];
#pragma unroll
            for (int i = 0; i < 2; ++i)
                af[i] = *(const short8*)&Ap[(i * 16 + l16) * 136 + kk * 32 + quad * 8];
#pragma unroll
            for (int j = 0; j < 4; ++j)
                bfr[j] = *(const short8*)(baseW1 + (size_t)(j * 32 + it * 4 + kk) * 512);
#pragma unroll
            for (int i = 0; i < 2; ++i)
#pragma unroll
                for (int j = 0; j < 4; ++j)
                    acc[i][j] = __builtin_amdgcn_mfma_f32_16x16x32_bf16(af[i], bfr[j], acc[i][j], 0, 0, 0);
        }
    }

    // meas (C-layout) -> Ms row-major [m][s]; wave strip = cols [64w, 64w+64)
#pragma unroll
    for (int i = 0; i < 2; ++i)
#pragma unroll
        for (int r = 0; r < 4; ++r) {
            const int row = i * 16 + quad * 4 + r;
#pragma unroll
            for (int j = 0; j < 4; ++j)
                Ms[row * 264 + wave * 64 + j * 16 + l16] = __float2bfloat16(acc[i][j][r]);
        }
    __syncthreads();

    // ---------------- phase 2 (barrier-free) ----------------
    float* ybase = Y + (size_t)blk * 32768;
#pragma unroll 1
    for (int c = 0; c < 4; ++c) {
        floatx4 a2[2][4];
#pragma unroll
        for (int i = 0; i < 2; ++i)
#pragma unroll
            for (int j = 0; j < 4; ++j) a2[i][j] = {0.f, 0.f, 0.f, 0.f};
        const __hip_bfloat16* w2 = baseW2 + (size_t)c * 65536;
#pragma unroll
        for (int ks = 0; ks < 8; ++ks) {
            short8 af[2], bfr[4];
#pragma unroll
            for (int i = 0; i < 2; ++i)
                af[i] = *(const short8*)&Ms[(i * 16 + l16) * 264 + ks * 32 + quad * 8];
#pragma unroll
            for (int j = 0; j < 4; ++j)
                bfr[j] = *(const short8*)(w2 + (size_t)j * 4096 + ks * 512);
#pragma unroll
            for (int i = 0; i < 2; ++i)
#pragma unroll
                for (int j = 0; j < 4; ++j)
                    a2[i][j] = __builtin_amdgcn_mfma_f32_16x16x32_bf16(af[i], bfr[j], a2[i][j], 0, 0, 0);
        }
        // fold epilogue: m = patch; col = c*256 + wave*64 + j*16 + l16 -> (kh,kw)
#pragma unroll
        for (int i = 0; i < 2; ++i)
#pragma unroll
            for (int r = 0; r < 4; ++r) {
                const int m = i * 16 + quad * 4 + r;
#pragma unroll
                for (int j = 0; j < 4; ++j) {
                    const int col = c * 256 + wave * 64 + j * 16 + l16;
                    const int kh = col >> 5, kw = col & 31;
                    ybase[kh * 1024 + m * 32 + kw] = a2[i][j][r];
                }
            }
    }
}

// ---------------------------------------------------------------------------
// Workspace: wsb_t bf16 [262144] @ 0 (524288 B); wib_t bf16 [262144]
// @ 524288 (524288 B). Total 1 MB.
// ---------------------------------------------------------------------------
extern "C" void kernel_launch(void* const* d_in, const int* in_sizes, int n_in,
                              void* d_out, int out_size, void* d_ws, size_t ws_size,
                              hipStream_t stream) {
    const float* x        = (const float*)d_in[0];
    const float* w_sample = (const float*)d_in[1];
    const float* w_init   = (const float*)d_in[2];
    float* y = (float*)d_out;
    char* ws = (char*)d_ws;

    __hip_bfloat16* wsb_t = (__hip_bfloat16*)(ws);
    __hip_bfloat16* wib_t = (__hip_bfloat16*)(ws + (size_t)524288);

    prepack_kernel<<<256, 256, 0, stream>>>(w_sample, w_init, wsb_t, wib_t);
    fused_kernel<<<512, 256, 0, stream>>>(x, wsb_t, wib_t, y);
}